// Round 5
// baseline (120.949 us; speedup 1.0000x reference)
//
#include <hip/hip_runtime.h>

#define N_ 8
#define C_ 64
#define L_ 512
#define D_ 64
#define TI 8          // rows per block
#define JT 71         // band cols per block: TI-1 + 64
#define KST 68        // k2b[jj][d] stride: mult of 4, ==4 mod 32 -> balanced b128
#define XST 76        // xs[c][jj] stride: mult of 4, ==12 mod 32 -> balanced b128
#define AST 76        // ash row stride

#define C2F 2.8853900817779268f   // 2*log2(e)
#define MAGIC 0x11C0FFEEu         // != 0xAAAAAAAA ws poison

__device__ __forceinline__ float rcp_f(float x) { return __builtin_amdgcn_rcpf(x); }
__device__ __forceinline__ float ex2(float x)   { return __builtin_amdgcn_exp2f(x); }

// Single fused kernel: per-block proj of own 8 rows -> flag handshake ->
// banded scores + softmax + AV.  grid 512 = (n = bx&7, t = bx>>3), 512 thr.
__global__ __launch_bounds__(512, 4) void fused_kernel(
    const float* __restrict__ x, const float* __restrict__ Wx,
    const float* __restrict__ Wt, const float* __restrict__ bh,
    const float* __restrict__ Wa,
    float* __restrict__ K2L, unsigned int* __restrict__ done,
    float* __restrict__ vout, float* __restrict__ aout)
{
  __shared__ float xs[C_ * XST];    // [c][jj] band x tile
  __shared__ float k2b[JT * KST];   // [jj][d]; doubles as proj scratch (16 KB)
  __shared__ float qs[TI * D_];     // [l][d] own-row q2
  __shared__ float ash[TI * AST];   // [row][jj] shifted a, zero-padded
  __shared__ float vs[C_][9];       // [c][row]

  const int tid  = threadIdx.x;
  const int lane = tid & 63;
  const int bx   = blockIdx.x;
  const int n    = bx & 7;          // consecutive-XCD blocks get distinct n:
  const int t    = bx >> 3;         // same-XCD neighbors are adjacent t
  const int i0   = t << 3;
  const int jbase = i0 - 32;

  // ---- stage xs[c][jj]: 1 float4 global -> 1 ds_write_b128 ----
  for (int idx = tid; idx < C_ * 18; idx += 512) {
    int c = idx / 18, qq = idx - c * 18;
    int jj = qq << 2;
    int j = jbase + jj;                      // j % 4 == 0: quad fully in or out
    float4 xv = {0.f, 0.f, 0.f, 0.f};
    if (j >= 0 && j < L_) xv = *(const float4*)(x + (n * C_ + c) * L_ + j);
    *(float4*)&xs[c * XST + jj] = xv;
  }
  __syncthreads();

  // ---- proj of own 8 rows: partial dots over a c-quarter ----
  {
    const int dq = lane & 15, which = (lane >> 4) & 1, l2 = lane >> 5;
    const int w_idx = tid >> 6, cq = w_idx & 3, lh = w_idx >> 2;
    const int lA = lh * 4 + l2 * 2, lB = lA + 1;
    const float* W = which ? Wx : Wt;
    float4 accA = {0.f, 0.f, 0.f, 0.f}, accB = {0.f, 0.f, 0.f, 0.f};
    #pragma unroll 4
    for (int c = cq * 16; c < cq * 16 + 16; ++c) {
      float4 wv = *(const float4*)(W + c * D_ + dq * 4);
      float xA = xs[c * XST + 32 + lA];
      float xB = xs[c * XST + 32 + lB];
      accA.x = fmaf(xA, wv.x, accA.x); accA.y = fmaf(xA, wv.y, accA.y);
      accA.z = fmaf(xA, wv.z, accA.z); accA.w = fmaf(xA, wv.w, accA.w);
      accB.x = fmaf(xB, wv.x, accB.x); accB.y = fmaf(xB, wv.y, accB.y);
      accB.z = fmaf(xB, wv.z, accB.z); accB.w = fmaf(xB, wv.w, accB.w);
    }
    *(float4*)&k2b[(((cq * 2 + which) * 8 + lA) * 16 + dq) * 4] = accA;
    *(float4*)&k2b[(((cq * 2 + which) * 8 + lB) * 16 + dq) * 4] = accB;
  }
  __syncthreads();
  // ---- combine c-quarters; q -> qs LDS, k -> K2L global ----
  if (tid < 256) {
    const int which = tid >> 7, l = (tid >> 4) & 7, dq = tid & 15;
    float4 s = {0.f, 0.f, 0.f, 0.f};
    #pragma unroll
    for (int cq = 0; cq < 4; ++cq) {
      float4 p = *(const float4*)&k2b[(((cq * 2 + which) * 8 + l) * 16 + dq) * 4];
      s.x += p.x; s.y += p.y; s.z += p.z; s.w += p.w;
    }
    if (which == 0) {
      float4 b = *(const float4*)(bh + dq * 4);
      float4 q = {(s.x + b.x) * C2F, (s.y + b.y) * C2F,
                  (s.z + b.z) * C2F, (s.w + b.w) * C2F};
      *(float4*)&qs[l * D_ + dq * 4] = q;
    } else {
      float4 k = {s.x * C2F, s.y * C2F, s.z * C2F, s.w * C2F};
      *(float4*)(K2L + ((size_t)(n * L_ + i0 + l)) * D_ + dq * 4) = k;
    }
  }
  __threadfence();                 // publish K2L rows (agent scope)
  __syncthreads();
  // ---- flag own tile; wait for band neighbors (t-4..t+4, same n/XCD) ----
  if (tid == 0)
    __hip_atomic_store(&done[(n << 6) + t], MAGIC,
                       __ATOMIC_RELEASE, __HIP_MEMORY_SCOPE_AGENT);
  if (tid < 9) {
    int t2 = t - 4 + tid;
    if (t2 >= 0 && t2 < 64 && t2 != t)
      while (__hip_atomic_load(&done[(n << 6) + t2],
                               __ATOMIC_ACQUIRE, __HIP_MEMORY_SCOPE_AGENT) != MAGIC)
        __builtin_amdgcn_s_sleep(1);
  }
  __syncthreads();
  // per-wave acquire (cache-inv) ordered before this wave's K2L reads
  (void)__hip_atomic_load(&done[(n << 6) + t],
                          __ATOMIC_ACQUIRE, __HIP_MEMORY_SCOPE_AGENT);

  // ---- stage k2b[jj][d] from K2L band ----
  for (int idx = tid; idx < JT * 16; idx += 512) {
    int jj = idx >> 4, d4 = (idx & 15) << 2;
    int j = jbase + jj;
    float4 kv = {0.f, 0.f, 0.f, 0.f};
    if (j >= 0 && j < L_) kv = *(const float4*)(K2L + ((size_t)n * L_ + j) * D_ + d4);
    *(float4*)&k2b[jj * KST + d4] = kv;
  }
  __syncthreads();

  // ---- score row i = i0 + wu: lane = band position, b128 k-reads ----
  const int wu = __builtin_amdgcn_readfirstlane(tid >> 6);
  const int i  = i0 + wu;
  const float* kp = &k2b[(wu + lane) * KST];
  const float* qp = &qs[wu * D_];           // uniform -> broadcast b128
  float a0 = 0.f, a1 = 0.f, a2 = 0.f, a3 = 0.f;
  #pragma unroll 4
  for (int dc = 0; dc < D_; dc += 4) {
    float4 kv = *(const float4*)(kp + dc);
    float4 qv = *(const float4*)(qp + dc);
    float4 wv = *(const float4*)(Wa + dc);  // uniform -> s_load
    a0 = fmaf(rcp_f(ex2(kv.x + qv.x) + 1.f), wv.x, a0);   // sigma(-2x)*Wa_d
    a1 = fmaf(rcp_f(ex2(kv.y + qv.y) + 1.f), wv.y, a1);
    a2 = fmaf(rcp_f(ex2(kv.z + qv.z) + 1.f), wv.z, a2);
    a3 = fmaf(rcp_f(ex2(kv.w + qv.w) + 1.f), wv.w, a3);
  }
  const float acc = (a0 + a1) + (a2 + a3);

  // ---- band softmax (raw = const - 2*acc -> band max == acc min) ----
  const int j = i - 32 + lane;
  const bool valid = (j >= 0) && (j < L_);
  float m = valid ? acc : 1e30f;
  #pragma unroll
  for (int off = 32; off; off >>= 1) m = fminf(m, __shfl_xor(m, off, 64));
  float p = valid ? ex2(C2F * (m - acc)) : 0.f;
  float s = p;
  #pragma unroll
  for (int off = 32; off; off >>= 1) s += __shfl_xor(s, off, 64);
  const float av = p * rcp_f(s + 1e-6f);

  // shifted a row: ash[wu][jj] = a[jj - wu], zero elsewhere (same-wave use)
  float* arow_s = &ash[wu * AST];
  arow_s[lane] = 0.f;
  if (lane < AST - 64) arow_s[64 + lane] = 0.f;
  arow_s[wu + lane] = av;

  // coalesced a-row global write: rotate so lane L holds col === L (mod 64)
  {
    const int src  = (lane - i + 32) & 63;
    const float ar = __shfl(av, src, 64);
    const int jsrc = i - 32 + src;            // === lane (mod 64)
    const int seg  = (jsrc >= 0) ? (jsrc >> 6) : 9;
    float* arow = aout + (size_t)(n * L_ + i) * L_;
    #pragma unroll
    for (int s8 = 0; s8 < 8; ++s8)
      arow[s8 * 64 + lane] = (s8 == seg) ? ar : 0.f;
  }

  // ---- v(row i) = sum_jj ash[jj] * xs[c][jj], lane = c, all-b128 ----
  {
    const int qstart = wu & ~3;               // quad window [qstart, qstart+68)
    float v = 0.f;
    const float* xp = &xs[lane * XST];
    #pragma unroll 4
    for (int tq = 0; tq < 17; ++tq) {
      const int jj = qstart + 4 * tq;
      float4 a4 = *(const float4*)(arow_s + jj);   // uniform broadcast
      float4 xq = *(const float4*)(xp + jj);       // balanced strided b128
      v = fmaf(a4.x, xq.x, v);
      v = fmaf(a4.y, xq.y, v);
      v = fmaf(a4.z, xq.z, v);
      v = fmaf(a4.w, xq.w, v);
    }
    vs[lane][wu] = v;
  }
  __syncthreads();
  {
    int c = tid >> 3, il = tid & 7;
    if (tid < 512) vout[((size_t)n * C_ + c) * L_ + i0 + il] = vs[c][il];
  }
}

extern "C" void kernel_launch(void* const* d_in, const int* in_sizes, int n_in,
                              void* d_out, int out_size, void* d_ws, size_t ws_size,
                              hipStream_t stream) {
  const float* x  = (const float*)d_in[0];
  const float* Wx = (const float*)d_in[1];   // key proj
  const float* Wt = (const float*)d_in[2];   // query proj
  const float* bh = (const float*)d_in[3];
  const float* Wa = (const float*)d_in[4];
  // d_in[5] (ba) cancels in the softmax: unused.

  float* vout = (float*)d_out;               // N*C*L
  float* aout = vout + N_ * C_ * L_;         // N*L*L
  float* K2L  = (float*)d_ws;                // N*L*D (l-major), 1 MB
  unsigned int* done = (unsigned int*)((char*)d_ws + (size_t)N_ * L_ * D_ * 4);

  fused_kernel<<<512, 512, 0, stream>>>(x, Wx, Wt, bh, Wa, K2L, done, vout, aout);
}

// Round 6
// 18.770 us; speedup vs baseline: 6.4437x; 6.4437x over previous
//
#include <hip/hip_runtime.h>

#define N_ 8
#define C_ 64
#define L_ 512
#define D_ 64
#define TI 8          // rows per block
#define JT 71         // band cols per block: TI-1 + 64
#define KST 68        // k2b[jj][d] stride: mult of 4, ==4 mod 32 -> b128 floor
#define XST 76        // xs[c][jj] stride: mult of 4, ==12 mod 32 -> b128 floor
#define AST 76        // ash row stride

#define C2F 2.8853900817779268f   // 2*log2(e)

__device__ __forceinline__ float rcp_f(float x) { return __builtin_amdgcn_rcpf(x); }
__device__ __forceinline__ float ex2(float x)   { return __builtin_amdgcn_exp2f(x); }

// Single fused kernel, fully independent blocks (no inter-block comm):
// each block redundantly computes the k2 band it needs.
// grid 512 = (n = bx&7 -> XCD-local batch, t = bx>>3), 512 thr = 8 waves.
__global__ __launch_bounds__(512, 4) void fused_kernel(
    const float* __restrict__ x, const float* __restrict__ Wx,
    const float* __restrict__ Wt, const float* __restrict__ bh,
    const float* __restrict__ Wa,
    float* __restrict__ vout, float* __restrict__ aout)
{
  __shared__ float xs[C_ * XST];    // [c][jj] band x tile
  __shared__ float k2b[72 * KST];   // [jj][d] band keys (scaled)
  __shared__ float qs[TI * D_];     // [row][d] own-row q (scaled, +bias)
  __shared__ float ash[TI * AST];   // [row][jj] shifted a, zero-padded
  __shared__ float vs[C_][9];       // [c][row]

  const int tid  = threadIdx.x;
  const int lane = tid & 63;
  const int bx   = blockIdx.x;
  const int n    = bx & 7;          // consecutive blocks -> distinct n (XCD-local x)
  const int t    = bx >> 3;
  const int i0   = t << 3;
  const int jbase = i0 - 32;

  // ---- stage xs[c][jj]: 1 float4 global -> 1 ds_write_b128 ----
  for (int idx = tid; idx < C_ * 18; idx += 512) {
    int c = idx / 18, qq = idx - c * 18;
    int jj = qq << 2;
    int j = jbase + jj;                      // j % 4 == 0: quad fully in or out
    float4 xv = {0.f, 0.f, 0.f, 0.f};
    if (j >= 0 && j < L_) xv = *(const float4*)(x + (n * C_ + c) * L_ + j);
    *(float4*)&xs[c * XST + jj] = xv;
  }
  __syncthreads();

  const int w = __builtin_amdgcn_readfirstlane(tid >> 6);   // wave id, uniform

  // ---- k2 main: wave w owns d-slab [8w,8w+8), lane = band col jj ----
  {
    const float* wxp = Wx + 8 * w;           // uniform -> s_load rows
    float4 p0 = {0.f, 0.f, 0.f, 0.f}, p1 = {0.f, 0.f, 0.f, 0.f};
    #pragma unroll 8
    for (int c = 0; c < C_; ++c) {
      float xv = xs[c * XST + lane];                        // conflict-free b32
      float4 wa = *(const float4*)(wxp + c * D_);           // uniform
      float4 wb = *(const float4*)(wxp + c * D_ + 4);
      p0.x = fmaf(xv, wa.x, p0.x); p0.y = fmaf(xv, wa.y, p0.y);
      p0.z = fmaf(xv, wa.z, p0.z); p0.w = fmaf(xv, wa.w, p0.w);
      p1.x = fmaf(xv, wb.x, p1.x); p1.y = fmaf(xv, wb.y, p1.y);
      p1.z = fmaf(xv, wb.z, p1.z); p1.w = fmaf(xv, wb.w, p1.w);
    }
    float4 o0 = {p0.x * C2F, p0.y * C2F, p0.z * C2F, p0.w * C2F};
    float4 o1 = {p1.x * C2F, p1.y * C2F, p1.z * C2F, p1.w * C2F};
    *(float4*)&k2b[lane * KST + 8 * w]     = o0;
    *(float4*)&k2b[lane * KST + 8 * w + 4] = o1;
  }
  // ---- q rows: wave w owns row w, lane = d (coalesced L1 W reads) ----
  {
    float a = 0.f;
    const float* wtp = Wt + lane;
    #pragma unroll 8
    for (int c = 0; c < C_; ++c)
      a = fmaf(xs[c * XST + 32 + w], wtp[c * D_], a);       // x uniform bcast
    qs[w * D_ + lane] = (a + bh[lane]) * C2F;
  }
  // ---- k2 tail cols jj = 64..70: wave w (<7) owns col 64+w, lane = d ----
  if (w < 7) {
    float a = 0.f;
    const float* wxp = Wx + lane;
    #pragma unroll 8
    for (int c = 0; c < C_; ++c)
      a = fmaf(xs[c * XST + 64 + w], wxp[c * D_], a);
    k2b[(64 + w) * KST + lane] = a * C2F;
  }
  __syncthreads();

  // ---- score row i = i0 + w: lane = band position, b128 k-reads ----
  const int i = i0 + w;
  const float* kp = &k2b[(w + lane) * KST];
  const float* qp = &qs[w * D_];            // uniform -> broadcast b128
  float a0 = 0.f, a1 = 0.f, a2 = 0.f, a3 = 0.f;
  #pragma unroll 4
  for (int dc = 0; dc < D_; dc += 4) {
    float4 kv = *(const float4*)(kp + dc);
    float4 qv = *(const float4*)(qp + dc);
    float4 wv = *(const float4*)(Wa + dc);  // uniform -> s_load
    a0 = fmaf(rcp_f(ex2(kv.x + qv.x) + 1.f), wv.x, a0);   // sigma(-2x)*Wa_d
    a1 = fmaf(rcp_f(ex2(kv.y + qv.y) + 1.f), wv.y, a1);
    a2 = fmaf(rcp_f(ex2(kv.z + qv.z) + 1.f), wv.z, a2);
    a3 = fmaf(rcp_f(ex2(kv.w + qv.w) + 1.f), wv.w, a3);
  }
  const float acc = (a0 + a1) + (a2 + a3);

  // ---- band softmax (raw = const - 2*acc -> band max == acc min) ----
  const int j = i - 32 + lane;
  const bool valid = (j >= 0) && (j < L_);
  float m = valid ? acc : 1e30f;
  #pragma unroll
  for (int off = 32; off; off >>= 1) m = fminf(m, __shfl_xor(m, off, 64));
  float p = valid ? ex2(C2F * (m - acc)) : 0.f;
  float s = p;
  #pragma unroll
  for (int off = 32; off; off >>= 1) s += __shfl_xor(s, off, 64);
  const float av = p * rcp_f(s + 1e-6f);

  // shifted a row: ash[w][jj] = a[jj - w], zero elsewhere (same-wave use only)
  float* arow_s = &ash[w * AST];
  arow_s[lane] = 0.f;
  if (lane < AST - 64) arow_s[64 + lane] = 0.f;
  arow_s[w + lane] = av;

  // coalesced a-row global write: rotate so lane L holds col === L (mod 64)
  {
    const int src  = (lane - i + 32) & 63;
    const float ar = __shfl(av, src, 64);
    const int jsrc = i - 32 + src;            // === lane (mod 64)
    const int seg  = (jsrc >= 0) ? (jsrc >> 6) : 9;
    float* arow = aout + (size_t)(n * L_ + i) * L_;
    #pragma unroll
    for (int s8 = 0; s8 < 8; ++s8)
      arow[s8 * 64 + lane] = (s8 == seg) ? ar : 0.f;
  }

  // ---- v(row i) = sum_jj ash[jj] * xs[c][jj], lane = c, all-b128 ----
  {
    const int qstart = w & ~3;                // quad window [qstart, qstart+68)
    float v = 0.f;
    const float* xp = &xs[lane * XST];
    #pragma unroll 4
    for (int tq = 0; tq < 17; ++tq) {
      const int jj = qstart + 4 * tq;
      float4 a4 = *(const float4*)(arow_s + jj);   // uniform broadcast
      float4 xq = *(const float4*)(xp + jj);       // strided b128, floor banks
      v = fmaf(a4.x, xq.x, v);
      v = fmaf(a4.y, xq.y, v);
      v = fmaf(a4.z, xq.z, v);
      v = fmaf(a4.w, xq.w, v);
    }
    vs[lane][w] = v;
  }
  __syncthreads();
  {
    int c = tid >> 3, il = tid & 7;
    vout[((size_t)n * C_ + c) * L_ + i0 + il] = vs[c][il];
  }
}

extern "C" void kernel_launch(void* const* d_in, const int* in_sizes, int n_in,
                              void* d_out, int out_size, void* d_ws, size_t ws_size,
                              hipStream_t stream) {
  const float* x  = (const float*)d_in[0];
  const float* Wx = (const float*)d_in[1];   // key proj
  const float* Wt = (const float*)d_in[2];   // query proj
  const float* bh = (const float*)d_in[3];
  const float* Wa = (const float*)d_in[4];
  // d_in[5] (ba) cancels in the softmax: unused.
  (void)d_ws; (void)ws_size;

  float* vout = (float*)d_out;               // N*C*L
  float* aout = vout + N_ * C_ * L_;         // N*L*L

  fused_kernel<<<512, 512, 0, stream>>>(x, Wx, Wt, bh, Wa, vout, aout);
}

// Round 7
// 15.264 us; speedup vs baseline: 7.9238x; 1.2297x over previous
//
#include <hip/hip_runtime.h>

#define N_ 8
#define C_ 64
#define L_ 512
#define D_ 64
#define TI 8          // rows per block
#define JT 71         // band cols per block: TI-1 + 64
#define KST 68        // k2b row stride (dwords): mult of 4, ==4 mod 32
#define XST 76        // xs row stride (dwords): mult of 4, ==12 mod 32
#define XBST 88       // xb row stride (f16): 176B, 16B-aligned, 12-mod-32 banks
#define AST 76        // ash row stride

#define C2F 2.8853900817779268f   // 2*log2(e)

typedef _Float16 f16x8 __attribute__((ext_vector_type(8)));
typedef float    f32x4 __attribute__((ext_vector_type(4)));

__device__ __forceinline__ float rcp_f(float x) { return __builtin_amdgcn_rcpf(x); }
__device__ __forceinline__ float ex2(float x)   { return __builtin_amdgcn_exp2f(x); }

// Single fused kernel, independent blocks; per-block band projection done
// on the matrix pipe (f16 MFMA, f32 accumulate).
// grid 512 = (n = bx&7 -> XCD-local batch, t = bx>>3), 512 thr = 8 waves.
__global__ __launch_bounds__(512, 4) void fused_kernel(
    const float* __restrict__ x, const float* __restrict__ Wx,
    const float* __restrict__ Wt, const float* __restrict__ bh,
    const float* __restrict__ Wa,
    float* __restrict__ vout, float* __restrict__ aout)
{
  __shared__ __attribute__((aligned(16))) float    xs[C_ * XST];   // [c][jj] f32 (AV)
  __shared__ __attribute__((aligned(16))) _Float16 xb[80 * XBST];  // [jj][c] f16*C2F (MFMA A)
  __shared__ __attribute__((aligned(16))) float    k2b[96 * KST];  // rows 0..70 k2, 80..87 q2
  __shared__ float ash[TI * AST];   // [row][jj] shifted a, zero-padded
  __shared__ float vs[C_][9];       // [c][row]

  const int tid  = threadIdx.x;
  const int lane = tid & 63;
  const int bx   = blockIdx.x;
  const int n    = bx & 7;          // consecutive blocks -> distinct n (XCD-local x)
  const int t    = bx >> 3;
  const int i0   = t << 3;
  const int jbase = i0 - 32;

  // ---- stage xs (f32 quad) + xb (f16 transposed scatter, C2F folded) ----
  for (int idx = tid; idx < C_ * 18; idx += 512) {
    int c = idx / 18, qq = idx - c * 18;
    int jj = qq << 2;
    int j = jbase + jj;                      // j % 4 == 0: quad fully in or out
    float4 xv = {0.f, 0.f, 0.f, 0.f};
    if (j >= 0 && j < L_) xv = *(const float4*)(x + (n * C_ + c) * L_ + j);
    *(float4*)&xs[c * XST + jj] = xv;
    _Float16* xbp = xb + c;
    xbp[(jj + 0) * XBST] = (_Float16)(xv.x * C2F);
    xbp[(jj + 1) * XBST] = (_Float16)(xv.y * C2F);
    xbp[(jj + 2) * XBST] = (_Float16)(xv.z * C2F);
    xbp[(jj + 3) * XBST] = (_Float16)(xv.w * C2F);
  }
  __syncthreads();

  const int w = __builtin_amdgcn_readfirstlane(tid >> 6);   // wave id, uniform

  // ---- MFMA projection: wave w (<6) owns one 16-row M-tile ----
  // M-tiles 0..4: k2 band rows 16w (B = Wx); tile 5: q rows (band 32..47, B = Wt)
  if (w < 6) {
    const int abase = (w < 5) ? w * 16 : 32;
    const float* Wm = (w < 5) ? Wx : Wt;
    const int l15 = lane & 15, g = lane >> 4;
    const _Float16* ap = xb + (abase + l15) * XBST + g * 8;
    const f16x8 af0 = *(const f16x8*)(ap);          // k = c 0..31 slice
    const f16x8 af1 = *(const f16x8*)(ap + 32);     // k = c 32..63 slice
    const int drow = ((w < 5) ? w * 16 : 80) + g * 4;
    #pragma unroll
    for (int nt = 0; nt < 4; ++nt) {
      f32x4 acc = {0.f, 0.f, 0.f, 0.f};
      #pragma unroll
      for (int kk = 0; kk < 2; ++kk) {
        const float* bp = Wm + (g * 8 + kk * 32) * D_ + nt * 16 + l15;
        f16x8 bf;
        bf[0] = (_Float16)bp[0 * D_];
        bf[1] = (_Float16)bp[1 * D_];
        bf[2] = (_Float16)bp[2 * D_];
        bf[3] = (_Float16)bp[3 * D_];
        bf[4] = (_Float16)bp[4 * D_];
        bf[5] = (_Float16)bp[5 * D_];
        bf[6] = (_Float16)bp[6 * D_];
        bf[7] = (_Float16)bp[7 * D_];
        acc = __builtin_amdgcn_mfma_f32_16x16x32_f16(kk ? af1 : af0, bf, acc, 0, 0, 0);
      }
      float* dp = &k2b[drow * KST + nt * 16 + l15];
      dp[0 * KST] = acc[0];
      dp[1 * KST] = acc[1];
      dp[2 * KST] = acc[2];
      dp[3 * KST] = acc[3];
    }
  }
  __syncthreads();
  // ---- q bias: rows 80..87 += bh*C2F (wave w handles its own q row) ----
  k2b[(80 + w) * KST + lane] += bh[lane] * C2F;
  __syncthreads();

  // ---- score row i = i0 + w: lane = band position, b128 k-reads ----
  const int i = i0 + w;
  const float* kp = &k2b[(w + lane) * KST];
  const float* qp = &k2b[(80 + w) * KST];   // uniform -> broadcast b128
  float a0 = 0.f, a1 = 0.f, a2 = 0.f, a3 = 0.f;
  #pragma unroll 4
  for (int dc = 0; dc < D_; dc += 4) {
    float4 kv = *(const float4*)(kp + dc);
    float4 qv = *(const float4*)(qp + dc);
    float4 wv = *(const float4*)(Wa + dc);  // uniform -> s_load
    a0 = fmaf(rcp_f(ex2(kv.x + qv.x) + 1.f), wv.x, a0);   // sigma(-2x)*Wa_d
    a1 = fmaf(rcp_f(ex2(kv.y + qv.y) + 1.f), wv.y, a1);
    a2 = fmaf(rcp_f(ex2(kv.z + qv.z) + 1.f), wv.z, a2);
    a3 = fmaf(rcp_f(ex2(kv.w + qv.w) + 1.f), wv.w, a3);
  }
  const float acc = (a0 + a1) + (a2 + a3);

  // ---- band softmax (raw = const - 2*acc -> band max == acc min) ----
  const int j = i - 32 + lane;
  const bool valid = (j >= 0) && (j < L_);
  float m = valid ? acc : 1e30f;
  #pragma unroll
  for (int off = 32; off; off >>= 1) m = fminf(m, __shfl_xor(m, off, 64));
  float p = valid ? ex2(C2F * (m - acc)) : 0.f;
  float s = p;
  #pragma unroll
  for (int off = 32; off; off >>= 1) s += __shfl_xor(s, off, 64);
  const float av = p * rcp_f(s + 1e-6f);

  // shifted a row: ash[w][jj] = a[jj - w], zero elsewhere (same-wave use only)
  float* arow_s = &ash[w * AST];
  arow_s[lane] = 0.f;
  if (lane < AST - 64) arow_s[64 + lane] = 0.f;
  arow_s[w + lane] = av;

  // coalesced a-row global write: rotate so lane L holds col === L (mod 64)
  {
    const int src  = (lane - i + 32) & 63;
    const float ar = __shfl(av, src, 64);
    const int jsrc = i - 32 + src;            // === lane (mod 64)
    const int seg  = (jsrc >= 0) ? (jsrc >> 6) : 9;
    float* arow = aout + (size_t)(n * L_ + i) * L_;
    #pragma unroll
    for (int s8 = 0; s8 < 8; ++s8)
      arow[s8 * 64 + lane] = (s8 == seg) ? ar : 0.f;
  }

  // ---- v(row i) = sum_jj ash[jj] * xs[c][jj], lane = c, all-b128 ----
  {
    const int qstart = w & ~3;                // quad window [qstart, qstart+68)
    float v = 0.f;
    const float* xp = &xs[lane * XST];
    #pragma unroll 4
    for (int tq = 0; tq < 17; ++tq) {
      const int jj = qstart + 4 * tq;
      float4 a4 = *(const float4*)(arow_s + jj);   // uniform broadcast
      float4 xq = *(const float4*)(xp + jj);       // strided b128, floor banks
      v = fmaf(a4.x, xq.x, v);
      v = fmaf(a4.y, xq.y, v);
      v = fmaf(a4.z, xq.z, v);
      v = fmaf(a4.w, xq.w, v);
    }
    vs[lane][w] = v;
  }
  __syncthreads();
  {
    int c = tid >> 3, il = tid & 7;
    vout[((size_t)n * C_ + c) * L_ + i0 + il] = vs[c][il];
  }
}

extern "C" void kernel_launch(void* const* d_in, const int* in_sizes, int n_in,
                              void* d_out, int out_size, void* d_ws, size_t ws_size,
                              hipStream_t stream) {
  const float* x  = (const float*)d_in[0];
  const float* Wx = (const float*)d_in[1];   // key proj
  const float* Wt = (const float*)d_in[2];   // query proj
  const float* bh = (const float*)d_in[3];
  const float* Wa = (const float*)d_in[4];
  // d_in[5] (ba) cancels in the softmax: unused.
  (void)d_ws; (void)ws_size;

  float* vout = (float*)d_out;               // N*C*L
  float* aout = vout + N_ * C_ * L_;         // N*L*L

  fused_kernel<<<512, 512, 0, stream>>>(x, Wx, Wt, bh, Wa, vout, aout);
}